// Round 1
// baseline (457.935 us; speedup 1.0000x reference)
//
#include <hip/hip_runtime.h>
#include <hip/hip_bf16.h>
#include <math.h>

// Problem: B=64, M=1, L=E=4096, H=64, DK=64
// out = ((attn_mix(softmax(cossim(qh,kh)), vh)) @ Wo + bo), all fp32.

#define TL 4096   // L == E
#define NB 64     // B == H

// ---------------------------------------------------------------------------
// GEMM body: Y[64][4096] = X[64][4096] @ W[4096][4096] + bias
// One block computes all 64 rows x 32 columns (cb..cb+31). BK=128.
// Xs stored transposed [k][row] (pad to 68) so the 4-row fragment is a float4.
// ---------------------------------------------------------------------------
__device__ __forceinline__ void gemm64_body(
    const float* __restrict__ X, const float* __restrict__ W,
    const float* __restrict__ bias, float* __restrict__ Y, int cb) {
  __shared__ float Xs[128][68];   // [k][row], padded
  __shared__ float Ws[128][32];   // [k][col]
  const int tid = threadIdx.x;
  const int lc = (tid & 15) * 2;  // local col base: 0..30 (2 cols/thread)
  const int lr = (tid >> 4) * 4;  // local row base: 0..60 (4 rows/thread)
  float acc[4][2] = {};

  for (int kb = 0; kb < TL; kb += 128) {
    // Stage X tile (64 rows x 128 k) -> transposed LDS. 2048 float4 loads.
#pragma unroll
    for (int i = 0; i < 8; ++i) {
      const int f = tid + 256 * i;      // 0..2047
      const int row = f >> 5;           // 32 float4 per row
      const int k4 = f & 31;
      const float4 v =
          *reinterpret_cast<const float4*>(&X[row * TL + kb + k4 * 4]);
      Xs[k4 * 4 + 0][row] = v.x;
      Xs[k4 * 4 + 1][row] = v.y;
      Xs[k4 * 4 + 2][row] = v.z;
      Xs[k4 * 4 + 3][row] = v.w;
    }
    // Stage W tile (128 k x 32 cols). 1024 float4 loads.
#pragma unroll
    for (int i = 0; i < 4; ++i) {
      const int f = tid + 256 * i;      // 0..1023
      const int k = f >> 3;             // 8 float4 per row
      const int q4 = f & 7;
      *reinterpret_cast<float4*>(&Ws[k][q4 * 4]) =
          *reinterpret_cast<const float4*>(&W[(size_t)(kb + k) * TL + cb + q4 * 4]);
    }
    __syncthreads();

#pragma unroll 4
    for (int k = 0; k < 128; ++k) {
      const float4 xv = *reinterpret_cast<const float4*>(&Xs[k][lr]);
      const float2 wv = *reinterpret_cast<const float2*>(&Ws[k][lc]);
      acc[0][0] += xv.x * wv.x; acc[0][1] += xv.x * wv.y;
      acc[1][0] += xv.y * wv.x; acc[1][1] += xv.y * wv.y;
      acc[2][0] += xv.z * wv.x; acc[2][1] += xv.z * wv.y;
      acc[3][0] += xv.w * wv.x; acc[3][1] += xv.w * wv.y;
    }
    __syncthreads();
  }

#pragma unroll
  for (int i = 0; i < 4; ++i) {
#pragma unroll
    for (int j = 0; j < 2; ++j) {
      const int col = cb + lc + j;
      Y[(lr + i) * TL + col] = acc[i][j] + bias[col];
    }
  }
}

// Fused triple projection: qh = q@Wq+bq, kh = k@Wk+bk, vh = v@Wv+bv
__global__ __launch_bounds__(256) void proj3_kernel(
    const float* __restrict__ q, const float* __restrict__ k,
    const float* __restrict__ v, const float* __restrict__ Wq,
    const float* __restrict__ Wk, const float* __restrict__ Wv,
    const float* __restrict__ bq, const float* __restrict__ bk,
    const float* __restrict__ bv, float* __restrict__ qh,
    float* __restrict__ kh, float* __restrict__ vh) {
  const float *X, *W, *bias;
  float* Y;
  if (blockIdx.y == 0)      { X = q; W = Wq; bias = bq; Y = qh; }
  else if (blockIdx.y == 1) { X = k; W = Wk; bias = bk; Y = kh; }
  else                      { X = v; W = Wv; bias = bv; Y = vh; }
  gemm64_body(X, W, bias, Y, blockIdx.x * 32);
}

// dist[b,h] = softmax_h( cossim(qh[b,h,:], kh[b,h,:]) )
__global__ __launch_bounds__(64) void dist_kernel(
    const float* __restrict__ qh, const float* __restrict__ kh,
    float* __restrict__ dist) {
  const int b = blockIdx.x;
  const int h = threadIdx.x;  // 0..63 == head
  const float* qr = qh + b * TL + h * 64;
  const float* kr = kh + b * TL + h * 64;
  float num = 0.f, qq = 0.f, kk = 0.f;
#pragma unroll
  for (int d = 0; d < 64; d += 4) {
    const float4 qv = *reinterpret_cast<const float4*>(&qr[d]);
    const float4 kv = *reinterpret_cast<const float4*>(&kr[d]);
    num += qv.x * kv.x + qv.y * kv.y + qv.z * kv.z + qv.w * kv.w;
    qq  += qv.x * qv.x + qv.y * qv.y + qv.z * qv.z + qv.w * qv.w;
    kk  += kv.x * kv.x + kv.y * kv.y + kv.z * kv.z + kv.w * kv.w;
  }
  const float den = fmaxf(sqrtf(qq) * sqrtf(kk), 1e-8f);
  float s = num / den;
  // softmax across the 64-lane wave (one head per lane)
  float m = s;
#pragma unroll
  for (int off = 32; off; off >>= 1) m = fmaxf(m, __shfl_xor(m, off));
  const float e = expf(s - m);
  float sum = e;
#pragma unroll
  for (int off = 32; off; off >>= 1) sum += __shfl_xor(sum, off);
  dist[b * 64 + h] = e / sum;
}

// attn[i, j*64+d] = sum_h dist[j,h] * vh[i, h*64+d]
__global__ __launch_bounds__(256) void attn_kernel(
    const float* __restrict__ dist, const float* __restrict__ vh,
    float* __restrict__ attn) {
  const int i = blockIdx.x;
  __shared__ float vrow[TL];
  __shared__ float ds[NB * NB];
  const int tid = threadIdx.x;
#pragma unroll
  for (int f = tid; f < 1024; f += 256) {
    *reinterpret_cast<float4*>(&vrow[f * 4]) =
        *reinterpret_cast<const float4*>(&vh[i * TL + f * 4]);
    *reinterpret_cast<float4*>(&ds[f * 4]) =
        *reinterpret_cast<const float4*>(&dist[f * 4]);
  }
  __syncthreads();
#pragma unroll
  for (int s = 0; s < 16; ++s) {
    const int c = tid + 256 * s;  // 0..4095
    const int j = c >> 6;
    const int d = c & 63;
    float sum = 0.f;
#pragma unroll
    for (int h = 0; h < 64; ++h) sum += ds[j * 64 + h] * vrow[h * 64 + d];
    attn[i * TL + c] = sum;
  }
}

// out = attn @ Wo + bo
__global__ __launch_bounds__(256) void out_kernel(
    const float* __restrict__ attn, const float* __restrict__ Wo,
    const float* __restrict__ bo, float* __restrict__ Yout) {
  gemm64_body(attn, Wo, bo, Yout, blockIdx.x * 32);
}

extern "C" void kernel_launch(void* const* d_in, const int* in_sizes, int n_in,
                              void* d_out, int out_size, void* d_ws,
                              size_t ws_size, hipStream_t stream) {
  const float* q  = (const float*)d_in[0];
  const float* k  = (const float*)d_in[1];
  const float* v  = (const float*)d_in[2];
  const float* Wq = (const float*)d_in[3];
  const float* bq = (const float*)d_in[4];
  const float* Wk = (const float*)d_in[5];
  const float* bk = (const float*)d_in[6];
  const float* Wv = (const float*)d_in[7];
  const float* bv = (const float*)d_in[8];
  const float* Wo = (const float*)d_in[9];
  const float* bo = (const float*)d_in[10];
  float* out = (float*)d_out;

  char* ws = (char*)d_ws;
  float* qh   = (float*)(ws);                       // 1 MiB
  float* kh   = (float*)(ws + (1u << 20));          // 1 MiB
  float* vh   = (float*)(ws + (2u << 20));          // 1 MiB
  float* dist = (float*)(ws + (3u << 20));          // 16 KiB
  float* attn = (float*)(ws + (3u << 20) + (1u << 16));  // 1 MiB

  proj3_kernel<<<dim3(128, 3), 256, 0, stream>>>(q, k, v, Wq, Wk, Wv, bq, bk,
                                                 bv, qh, kh, vh);
  dist_kernel<<<NB, 64, 0, stream>>>(qh, kh, dist);
  attn_kernel<<<NB, 256, 0, stream>>>(dist, vh, attn);
  out_kernel<<<128, 256, 0, stream>>>(attn, Wo, bo, out);
}

// Round 2
// 246.145 us; speedup vs baseline: 1.8604x; 1.8604x over previous
//
#include <hip/hip_runtime.h>
#include <hip/hip_bf16.h>
#include <math.h>

// B=64, M=1, L=E=4096, H=64, DK=64.
// Strategy: all GEMMs via bf16 split-precision MFMA (hi/lo), barrier-free
// W streaming (W read exactly once), split-K=2 with inline partial reduction.

#define TL 4096
#define NB 64

typedef float f32x4 __attribute__((ext_vector_type(4)));
typedef short bf16x8 __attribute__((ext_vector_type(8)));
typedef unsigned int uint32;
typedef unsigned short ushort16;

union B8 { uint32 u[4]; bf16x8 v; };

// Split two fp32 into packed hi-bf16 pair and lo-bf16 pair (truncation; lo
// captures the next 8 mantissa bits -> combined relative error ~2^-16).
__device__ __forceinline__ void split_pair(float f0, float f1, uint32& hp, uint32& lp) {
  uint32 u0 = __float_as_uint(f0), u1 = __float_as_uint(f1);
  hp = (u0 >> 16) | (u1 & 0xffff0000u);
  float l0 = f0 - __uint_as_float(u0 & 0xffff0000u);
  float l1 = f1 - __uint_as_float(u1 & 0xffff0000u);
  lp = (__float_as_uint(l0) >> 16) | (__float_as_uint(l1) & 0xffff0000u);
}

// ---------------------------------------------------------------------------
// prep: fp32 X[64][4096] -> Ah, Al bf16 (row-major, MFMA-A-ready)
// ---------------------------------------------------------------------------
struct Ptrs3 { const float* X[3]; ushort16* H[3]; ushort16* L[3]; };

__global__ __launch_bounds__(256) void prep_kernel(Ptrs3 p) {
  const int m = blockIdx.y;
  const int i = (blockIdx.x * 256 + threadIdx.x) * 4;
  const float4 f = *reinterpret_cast<const float4*>(p.X[m] + i);
  uint2 hv, lv;
  split_pair(f.x, f.y, hv.x, lv.x);
  split_pair(f.z, f.w, hv.y, lv.y);
  *reinterpret_cast<uint2*>(p.H[m] + i) = hv;
  *reinterpret_cast<uint2*>(p.L[m] + i) = lv;
}

// ---------------------------------------------------------------------------
// GEMM: P[ks][64][4096] (partial) = X[64][k-range] @ W[k-range][4096]
// One wave per (mat, ksplit, 16-col tile). Full M=64 per wave -> W read once.
// No LDS, no barriers. 12 MFMA per K-step (4 rowtiles x {hh, hl, lh}).
// ---------------------------------------------------------------------------
struct GemmArgs {
  const ushort16* Ah[4];
  const ushort16* Al[4];
  const float* W[4];
  float* P[4];
};

__device__ __forceinline__ void loadB(float (&f)[8], const float* wp) {
#pragma unroll
  for (int e = 0; e < 8; ++e) f[e] = wp[(size_t)e * TL];
}

__device__ __forceinline__ void kstep(const float (&f)[8],
                                      const ushort16* aph, const ushort16* apl,
                                      f32x4 (&acc)[4]) {
  B8 bh, bl;
#pragma unroll
  for (int e = 0; e < 4; ++e) split_pair(f[2 * e], f[2 * e + 1], bh.u[e], bl.u[e]);
#pragma unroll
  for (int rt = 0; rt < 4; ++rt) {
    const bf16x8 ah = *reinterpret_cast<const bf16x8*>(aph + rt * 16 * TL);
    const bf16x8 al = *reinterpret_cast<const bf16x8*>(apl + rt * 16 * TL);
    acc[rt] = __builtin_amdgcn_mfma_f32_16x16x32_bf16(ah, bh.v, acc[rt], 0, 0, 0);
    acc[rt] = __builtin_amdgcn_mfma_f32_16x16x32_bf16(ah, bl.v, acc[rt], 0, 0, 0);
    acc[rt] = __builtin_amdgcn_mfma_f32_16x16x32_bf16(al, bh.v, acc[rt], 0, 0, 0);
  }
}

__global__ __launch_bounds__(256) void mfma_gemm(GemmArgs ga) {
  const int g = blockIdx.x * 4 + (threadIdx.x >> 6);
  const int lane = threadIdx.x & 63;
  const int mat = g >> 9;        // 512 waves per matrix
  const int r = g & 511;
  const int ks = r >> 8;         // k-split half
  const int ct = r & 255;        // 16-col tile
  const int col = ct * 16 + (lane & 15);
  const int krow = (lane >> 4) * 8;
  const int k0 = ks * 2048;

  const ushort16* aph = ga.Ah[mat] + (size_t)(lane & 15) * TL + k0 + krow;
  const ushort16* apl = ga.Al[mat] + (size_t)(lane & 15) * TL + k0 + krow;
  const float* wp = ga.W[mat] + (size_t)(k0 + krow) * TL + col;
  const size_t WSTEP = (size_t)32 * TL;

  f32x4 acc[4] = {};
  float b0[8], b1[8];

  loadB(b0, wp); wp += WSTEP;
#pragma unroll 1
  for (int it = 0; it < 31; ++it) {
    loadB(b1, wp); wp += WSTEP;
    kstep(b0, aph, apl, acc); aph += 32; apl += 32;
    loadB(b0, wp); wp += WSTEP;
    kstep(b1, aph, apl, acc); aph += 32; apl += 32;
  }
  loadB(b1, wp);
  kstep(b0, aph, apl, acc); aph += 32; apl += 32;
  kstep(b1, aph, apl, acc);

  float* Pp = ga.P[mat] + (size_t)ks * NB * TL + col;
#pragma unroll
  for (int rt = 0; rt < 4; ++rt)
#pragma unroll
    for (int j = 0; j < 4; ++j)
      Pp[(size_t)(rt * 16 + (lane >> 4) * 4 + j) * TL] = acc[rt][j];
}

// ---------------------------------------------------------------------------
// dist[b,h] = softmax_h(cossim(qh[b,h,:], kh[b,h,:])); sums k-split partials
// and adds bias inline.
// ---------------------------------------------------------------------------
__global__ __launch_bounds__(64) void dist_kernel(
    const float* __restrict__ Pq, const float* __restrict__ Pk,
    const float* __restrict__ bq, const float* __restrict__ bk,
    float* __restrict__ dist) {
  const int b = blockIdx.x;
  const int h = threadIdx.x;
  const int base = b * TL + h * 64;
  float num = 0.f, qq = 0.f, kk = 0.f;
#pragma unroll
  for (int d = 0; d < 64; d += 4) {
    const f32x4 qv = *reinterpret_cast<const f32x4*>(&Pq[base + d]) +
                     *reinterpret_cast<const f32x4*>(&Pq[NB * TL + base + d]) +
                     *reinterpret_cast<const f32x4*>(&bq[h * 64 + d]);
    const f32x4 kv = *reinterpret_cast<const f32x4*>(&Pk[base + d]) +
                     *reinterpret_cast<const f32x4*>(&Pk[NB * TL + base + d]) +
                     *reinterpret_cast<const f32x4*>(&bk[h * 64 + d]);
#pragma unroll
    for (int e = 0; e < 4; ++e) {
      num += qv[e] * kv[e];
      qq += qv[e] * qv[e];
      kk += kv[e] * kv[e];
    }
  }
  const float den = fmaxf(sqrtf(qq) * sqrtf(kk), 1e-8f);
  float s = num / den;
  float m = s;
#pragma unroll
  for (int off = 32; off; off >>= 1) m = fmaxf(m, __shfl_xor(m, off));
  const float e = expf(s - m);
  float sum = e;
#pragma unroll
  for (int off = 32; off; off >>= 1) sum += __shfl_xor(sum, off);
  dist[b * 64 + h] = e / sum;
}

// ---------------------------------------------------------------------------
// attn row i: vrow = sum(Pv parts)+bv; attn[i,j*64+d] = sum_h dist[j,h]*vrow[h*64+d]
// Writes hi/lo bf16 directly (A-operand of the output GEMM).
// ---------------------------------------------------------------------------
__global__ __launch_bounds__(256) void attn_kernel(
    const float* __restrict__ Pv, const float* __restrict__ bv,
    const float* __restrict__ dist, ushort16* __restrict__ Ah,
    ushort16* __restrict__ Al) {
  const int i = blockIdx.x;
  __shared__ float vrow[TL];
  __shared__ float ds[NB * NB];
  const int tid = threadIdx.x;
#pragma unroll
  for (int f = tid; f < 1024; f += 256) {
    const f32x4 v = *reinterpret_cast<const f32x4*>(&Pv[i * TL + f * 4]) +
                    *reinterpret_cast<const f32x4*>(&Pv[NB * TL + i * TL + f * 4]) +
                    *reinterpret_cast<const f32x4*>(&bv[f * 4]);
    *reinterpret_cast<f32x4*>(&vrow[f * 4]) = v;
    *reinterpret_cast<f32x4*>(&ds[f * 4]) =
        *reinterpret_cast<const f32x4*>(&dist[f * 4]);
  }
  __syncthreads();
#pragma unroll
  for (int s = 0; s < 16; ++s) {
    const int c = tid + 256 * s;
    const int j = c >> 6, d = c & 63;
    float sum = 0.f;
#pragma unroll
    for (int h = 0; h < 64; ++h) sum += ds[j * 64 + h] * vrow[h * 64 + d];
    const uint32 u = __float_as_uint(sum);
    const float lo = sum - __uint_as_float(u & 0xffff0000u);
    Ah[i * TL + c] = (ushort16)(u >> 16);
    Al[i * TL + c] = (ushort16)(__float_as_uint(lo) >> 16);
  }
}

// out = sum(Po parts) + bo
__global__ __launch_bounds__(256) void reduce_kernel(
    const float* __restrict__ Po, const float* __restrict__ bo,
    float* __restrict__ out) {
  const int idx = (blockIdx.x * 256 + threadIdx.x) * 4;
  const f32x4 v = *reinterpret_cast<const f32x4*>(&Po[idx]) +
                  *reinterpret_cast<const f32x4*>(&Po[NB * TL + idx]) +
                  *reinterpret_cast<const f32x4*>(&bo[idx & (TL - 1)]);
  *reinterpret_cast<f32x4*>(&out[idx]) = v;
}

extern "C" void kernel_launch(void* const* d_in, const int* in_sizes, int n_in,
                              void* d_out, int out_size, void* d_ws,
                              size_t ws_size, hipStream_t stream) {
  const float* q  = (const float*)d_in[0];
  const float* k  = (const float*)d_in[1];
  const float* v  = (const float*)d_in[2];
  const float* Wq = (const float*)d_in[3];
  const float* bq = (const float*)d_in[4];
  const float* Wk = (const float*)d_in[5];
  const float* bk = (const float*)d_in[6];
  const float* Wv = (const float*)d_in[7];
  const float* bv = (const float*)d_in[8];
  const float* Wo = (const float*)d_in[9];
  const float* bo = (const float*)d_in[10];
  float* out = (float*)d_out;

  char* ws = (char*)d_ws;
  const size_t HB = 512u * 1024u;  // one bf16 half-buffer: 64*4096*2B
  ushort16* qAh = (ushort16*)(ws + 0 * HB);
  ushort16* qAl = (ushort16*)(ws + 1 * HB);
  ushort16* kAh = (ushort16*)(ws + 2 * HB);
  ushort16* kAl = (ushort16*)(ws + 3 * HB);
  ushort16* vAh = (ushort16*)(ws + 4 * HB);
  ushort16* vAl = (ushort16*)(ws + 5 * HB);
  ushort16* aAh = (ushort16*)(ws + 6 * HB);
  ushort16* aAl = (ushort16*)(ws + 7 * HB);
  float* Pq = (float*)(ws + 8 * HB);                      // 2 MiB (2 partials)
  float* Pk = (float*)(ws + 8 * HB + (2u << 20));
  float* Pv = (float*)(ws + 8 * HB + (4u << 20));
  float* Po = (float*)(ws + 8 * HB + (6u << 20));
  float* dist = (float*)(ws + 8 * HB + (8u << 20));       // 16 KiB

  // 1. split q,k,v into hi/lo bf16
  Ptrs3 p3;
  p3.X[0] = q; p3.X[1] = k; p3.X[2] = v;
  p3.H[0] = qAh; p3.H[1] = kAh; p3.H[2] = vAh;
  p3.L[0] = qAl; p3.L[1] = kAl; p3.L[2] = vAl;
  prep_kernel<<<dim3(256, 3), 256, 0, stream>>>(p3);

  // 2. the three projection GEMMs (1536 waves)
  GemmArgs gq;
  gq.Ah[0] = qAh; gq.Ah[1] = kAh; gq.Ah[2] = vAh; gq.Ah[3] = qAh;
  gq.Al[0] = qAl; gq.Al[1] = kAl; gq.Al[2] = vAl; gq.Al[3] = qAl;
  gq.W[0] = Wq; gq.W[1] = Wk; gq.W[2] = Wv; gq.W[3] = Wq;
  gq.P[0] = Pq; gq.P[1] = Pk; gq.P[2] = Pv; gq.P[3] = Pq;
  mfma_gemm<<<384, 256, 0, stream>>>(gq);

  // 3. cosine-sim + softmax (reduces q,k partials inline)
  dist_kernel<<<NB, 64, 0, stream>>>(Pq, Pk, bq, bk, dist);

  // 4. attention mix (reduces v partials inline), emits bf16 hi/lo attn
  attn_kernel<<<NB, 256, 0, stream>>>(Pv, bv, dist, aAh, aAl);

  // 5. output GEMM (512 waves)
  GemmArgs go;
  go.Ah[0] = aAh; go.Ah[1] = aAh; go.Ah[2] = aAh; go.Ah[3] = aAh;
  go.Al[0] = aAl; go.Al[1] = aAl; go.Al[2] = aAl; go.Al[3] = aAl;
  go.W[0] = Wo; go.W[1] = Wo; go.W[2] = Wo; go.W[3] = Wo;
  go.P[0] = Po; go.P[1] = Po; go.P[2] = Po; go.P[3] = Po;
  mfma_gemm<<<128, 256, 0, stream>>>(go);

  // 6. final reduce + bias -> out
  reduce_kernel<<<256, 256, 0, stream>>>(Po, bo, out);
}

// Round 3
// 134.658 us; speedup vs baseline: 3.4007x; 1.8279x over previous
//
#include <hip/hip_runtime.h>
#include <hip/hip_bf16.h>
#include <math.h>

// B=64, M=1, L=E=4096, H=64, DK=64.
// GEMMs: bf16 split-precision MFMA (hi/lo, 3 products), LDS-staged tiles via
// global_load_lds (width 16), double-buffered, split-K for parallelism.

#define TL 4096
#define NB 64
#define KSQ 4   // k-splits for QKV projections
#define KSO 8   // k-splits for output GEMM

typedef float f32x4 __attribute__((ext_vector_type(4)));
typedef short bf16x8 __attribute__((ext_vector_type(8)));
typedef unsigned int uint32;
typedef unsigned short u16;

union B8 { uint32 u[4]; bf16x8 v; };

// global_load_lds: per-lane global src, LDS dest = uniform base + lane*16.
#define GLOAD_LDS(g, l)                                                        \
  __builtin_amdgcn_global_load_lds(                                           \
      (const __attribute__((address_space(1))) void*)(g),                     \
      (__attribute__((address_space(3))) void*)(l), 16, 0, 0)

// Split two fp32 into packed hi-bf16 pair and lo-bf16 pair (truncation).
__device__ __forceinline__ void split_pair(float f0, float f1, uint32& hp,
                                           uint32& lp) {
  uint32 u0 = __float_as_uint(f0), u1 = __float_as_uint(f1);
  hp = (u0 >> 16) | (u1 & 0xffff0000u);
  float l0 = f0 - __uint_as_float(u0 & 0xffff0000u);
  float l1 = f1 - __uint_as_float(u1 & 0xffff0000u);
  lp = (__float_as_uint(l0) >> 16) | (__float_as_uint(l1) & 0xffff0000u);
}

// ---------------------------------------------------------------------------
// prep: fp32 X[64][4096] -> Ah, Al bf16 (row-major)
// ---------------------------------------------------------------------------
struct Ptrs3 { const float* X[3]; u16* H[3]; u16* L[3]; };

__global__ __launch_bounds__(256) void prep_kernel(Ptrs3 p) {
  const int m = blockIdx.y;
  const int i = (blockIdx.x * 256 + threadIdx.x) * 4;
  const float4 f = *reinterpret_cast<const float4*>(p.X[m] + i);
  uint2 hv, lv;
  split_pair(f.x, f.y, hv.x, lv.x);
  split_pair(f.z, f.w, hv.y, lv.y);
  *reinterpret_cast<uint2*>(p.H[m] + i) = hv;
  *reinterpret_cast<uint2*>(p.L[m] + i) = lv;
}

// ---------------------------------------------------------------------------
// Tiled GEMM: P[ks][64][4096] partial = X[64][krange] @ W[krange][4096]
// Block: 4 waves, 64 cols x full 64 rows x K-range (TL/KSplit).
// Per K64-tile: stage B fp32 [64k][64c] (16KB, col XOR-swizzled) + A hi/lo
// bf16 [8 chunks][64 rows][8k] (8KB+8KB) via global_load_lds; double-buffer.
// ---------------------------------------------------------------------------
struct GemmArgs {
  const u16* Ah[3];
  const u16* Al[3];
  const float* W[3];
  float* P[3];
};

template <int KSplit>
__global__ __launch_bounds__(256) void mfma_gemm(GemmArgs ga) {
  constexpr int KR = TL / KSplit;  // K per block
  constexpr int NT = KR / 64;      // K64 tiles
  __shared__ f32x4 smem4[4096];    // 64 KiB exactly: 2 x (16K B + 8K Ah + 8K Al)
  char* sb = (char*)smem4;

  const int tid = threadIdx.x;
  const int lane = tid & 63;
  const int w = tid >> 6;          // wave 0..3
  const int l15 = lane & 15, kg = lane >> 4;

  const int bid = blockIdx.x;
  const int mat = bid / (64 * KSplit);
  const int r = bid % (64 * KSplit);
  const int ks = r >> 6;
  const int ct = r & 63;
  const int k0 = ks * KR;
  const int colg = ct * 64;

  const float* W = ga.W[mat];
  const u16* Agh = ga.Ah[mat];
  const u16* Agl = ga.Al[mat];

  // Stage tile t into buffer `buf`. 8 global_load_lds per wave.
  auto STAGE = [&](int buf, int t) {
    const int kb = k0 + t * 64;
    char* Bb = sb + buf * 32768;
    char* Ahb = Bb + 16384;
    char* Alb = Bb + 24576;
    // B: wave w stages k-rows [w*16, w*16+16). LDS dword = k*64 + col',
    // col' = col ^ ((k>>3 & 1)<<4)  (store side pre-swizzles the SOURCE).
#pragma unroll
    for (int i = 0; i < 4; ++i) {
      const int krow = w * 16 + i * 4 + kg;  // per-lane k row (kg varies)
      const int scol = (l15 * 4) ^ (((krow >> 3) & 1) << 4);
      const float* gsrc = W + (size_t)(kb + krow) * TL + colg + scol;
      GLOAD_LDS(gsrc, Bb + (w * 16 + i * 4) * 256);
    }
    // A: wave w stages chunks 2w, 2w+1 (h and l). Layout [chunk][row][8k].
#pragma unroll
    for (int i = 0; i < 2; ++i) {
      const int c = w * 2 + i;
      GLOAD_LDS(Agh + (size_t)lane * TL + kb + c * 8, Ahb + c * 1024);
      GLOAD_LDS(Agl + (size_t)lane * TL + kb + c * 8, Alb + c * 1024);
    }
  };

  f32x4 acc[4] = {};
  STAGE(0, 0);
  __syncthreads();  // drains vmcnt(0) before barrier (compiler-emitted)

  const int bcol = (w * 16 + l15) ^ ((kg & 1) << 4);  // swizzled B read col

  for (int t = 0; t < NT; ++t) {
    const int buf = t & 1;
    if (t + 1 < NT) STAGE(buf ^ 1, t + 1);

    const char* Bb = sb + buf * 32768;
    const float* Bf = (const float*)Bb;
    const u16* Ahp = (const u16*)(Bb + 16384);
    const u16* Alp = (const u16*)(Bb + 24576);

#pragma unroll
    for (int ks2 = 0; ks2 < 2; ++ks2) {
      float f[8];
#pragma unroll
      for (int e = 0; e < 8; ++e)
        f[e] = Bf[(ks2 * 32 + kg * 8 + e) * 64 + bcol];
      B8 bh, bl;
#pragma unroll
      for (int e = 0; e < 4; ++e)
        split_pair(f[2 * e], f[2 * e + 1], bh.u[e], bl.u[e]);
#pragma unroll
      for (int rt = 0; rt < 4; ++rt) {
        const int ai = ((ks2 * 4 + kg) * 64 + rt * 16 + l15) * 8;
        const bf16x8 ah = *(const bf16x8*)(Ahp + ai);
        const bf16x8 al = *(const bf16x8*)(Alp + ai);
        acc[rt] = __builtin_amdgcn_mfma_f32_16x16x32_bf16(ah, bh.v, acc[rt], 0, 0, 0);
        acc[rt] = __builtin_amdgcn_mfma_f32_16x16x32_bf16(ah, bl.v, acc[rt], 0, 0, 0);
        acc[rt] = __builtin_amdgcn_mfma_f32_16x16x32_bf16(al, bh.v, acc[rt], 0, 0, 0);
      }
    }
    __syncthreads();
  }

  // C/D: col = lane&15, row = (lane>>4)*4 + reg (per 16-row tile rt)
  float* Pp = ga.P[mat] + ((size_t)ks * NB) * TL + colg + (w * 16 + l15);
#pragma unroll
  for (int rt = 0; rt < 4; ++rt)
#pragma unroll
    for (int j = 0; j < 4; ++j)
      Pp[(size_t)(rt * 16 + kg * 4 + j) * TL] = acc[rt][j];
}

// ---------------------------------------------------------------------------
// dist[b,h] = softmax_h(cossim(qh[b,h,:], kh[b,h,:])); sums KSQ partials+bias.
// ---------------------------------------------------------------------------
__global__ __launch_bounds__(64) void dist_kernel(
    const float* __restrict__ Pq, const float* __restrict__ Pk,
    const float* __restrict__ bq, const float* __restrict__ bk,
    float* __restrict__ dist) {
  const int b = blockIdx.x;
  const int h = threadIdx.x;
  float num = 0.f, qq = 0.f, kk = 0.f;
#pragma unroll
  for (int d = 0; d < 64; d += 4) {
    f32x4 qv = *(const f32x4*)&bq[h * 64 + d];
    f32x4 kv = *(const f32x4*)&bk[h * 64 + d];
#pragma unroll
    for (int s = 0; s < KSQ; ++s) {
      qv += *(const f32x4*)&Pq[((size_t)s * NB + b) * TL + h * 64 + d];
      kv += *(const f32x4*)&Pk[((size_t)s * NB + b) * TL + h * 64 + d];
    }
#pragma unroll
    for (int e = 0; e < 4; ++e) {
      num += qv[e] * kv[e];
      qq += qv[e] * qv[e];
      kk += kv[e] * kv[e];
    }
  }
  const float den = fmaxf(sqrtf(qq) * sqrtf(kk), 1e-8f);
  float s = num / den;
  float m = s;
#pragma unroll
  for (int off = 32; off; off >>= 1) m = fmaxf(m, __shfl_xor(m, off));
  const float e = expf(s - m);
  float sum = e;
#pragma unroll
  for (int off = 32; off; off >>= 1) sum += __shfl_xor(sum, off);
  dist[b * 64 + h] = e / sum;
}

// ---------------------------------------------------------------------------
// attn row i: vrow = sum(Pv parts)+bv; attn[i,j*64+d] = sum_h ds[j,h]*vrow[h*64+d]
// Emits hi/lo bf16 (A-operand of the output GEMM).
// ---------------------------------------------------------------------------
__global__ __launch_bounds__(256) void attn_kernel(
    const float* __restrict__ Pv, const float* __restrict__ bv,
    const float* __restrict__ dist, u16* __restrict__ Ah,
    u16* __restrict__ Al) {
  const int i = blockIdx.x;
  __shared__ float vrow[TL];
  __shared__ float ds[NB * NB];
  const int tid = threadIdx.x;
#pragma unroll
  for (int f = tid; f < 1024; f += 256) {
    f32x4 v = *(const f32x4*)&bv[f * 4];
#pragma unroll
    for (int s = 0; s < KSQ; ++s)
      v += *(const f32x4*)&Pv[((size_t)s * NB + i) * TL + f * 4];
    *reinterpret_cast<f32x4*>(&vrow[f * 4]) = v;
    *reinterpret_cast<f32x4*>(&ds[f * 4]) =
        *reinterpret_cast<const f32x4*>(&dist[f * 4]);
  }
  __syncthreads();
#pragma unroll
  for (int s = 0; s < 16; ++s) {
    const int c = tid + 256 * s;
    const int j = c >> 6, d = c & 63;
    float sum = 0.f;
#pragma unroll
    for (int h = 0; h < 64; ++h) sum += ds[j * 64 + h] * vrow[h * 64 + d];
    const uint32 u = __float_as_uint(sum);
    const float lo = sum - __uint_as_float(u & 0xffff0000u);
    Ah[i * TL + c] = (u16)(u >> 16);
    Al[i * TL + c] = (u16)(__float_as_uint(lo) >> 16);
  }
}

// out = sum over KSO partials + bo
__global__ __launch_bounds__(256) void reduce_kernel(
    const float* __restrict__ Po, const float* __restrict__ bo,
    float* __restrict__ out) {
  const int idx = (blockIdx.x * 256 + threadIdx.x) * 4;
  f32x4 v = *(const f32x4*)&bo[idx & (TL - 1)];
#pragma unroll
  for (int s = 0; s < KSO; ++s)
    v += *(const f32x4*)&Po[(size_t)s * NB * TL + idx];
  *reinterpret_cast<f32x4*>(&out[idx]) = v;
}

extern "C" void kernel_launch(void* const* d_in, const int* in_sizes, int n_in,
                              void* d_out, int out_size, void* d_ws,
                              size_t ws_size, hipStream_t stream) {
  const float* q  = (const float*)d_in[0];
  const float* k  = (const float*)d_in[1];
  const float* v  = (const float*)d_in[2];
  const float* Wq = (const float*)d_in[3];
  const float* bq = (const float*)d_in[4];
  const float* Wk = (const float*)d_in[5];
  const float* bk = (const float*)d_in[6];
  const float* Wv = (const float*)d_in[7];
  const float* bv = (const float*)d_in[8];
  const float* Wo = (const float*)d_in[9];
  const float* bo = (const float*)d_in[10];
  float* out = (float*)d_out;

  char* ws = (char*)d_ws;
  const size_t HB = 512u * 1024u;
  u16* qAh = (u16*)(ws + 0 * HB);
  u16* qAl = (u16*)(ws + 1 * HB);
  u16* kAh = (u16*)(ws + 2 * HB);
  u16* kAl = (u16*)(ws + 3 * HB);
  u16* vAh = (u16*)(ws + 4 * HB);
  u16* vAl = (u16*)(ws + 5 * HB);
  u16* aAh = (u16*)(ws + 6 * HB);
  u16* aAl = (u16*)(ws + 7 * HB);
  float* Pq = (float*)(ws + (4u << 20));   // 4 MiB (KSQ partials)
  float* Pk = (float*)(ws + (8u << 20));   // 4 MiB
  float* Pv = (float*)(ws + (12u << 20));  // 4 MiB
  // Po (KSO=8, 8 MiB) aliases [Pq,Pk]: both fully consumed by dist_kernel
  // before the output GEMM runs. Rewritten every launch -> deterministic.
  float* Po = Pq;
  float* dist = (float*)(ws + (16u << 20));  // 16 KiB

  // 1. split q,k,v into hi/lo bf16
  Ptrs3 p3;
  p3.X[0] = q; p3.X[1] = k; p3.X[2] = v;
  p3.H[0] = qAh; p3.H[1] = kAh; p3.H[2] = vAh;
  p3.L[0] = qAl; p3.L[1] = kAl; p3.L[2] = vAl;
  prep_kernel<<<dim3(256, 3), 256, 0, stream>>>(p3);

  // 2. QKV projections: 3 mats x 64 coltiles x KSQ ksplits = 768 blocks
  GemmArgs gq;
  gq.Ah[0] = qAh; gq.Ah[1] = kAh; gq.Ah[2] = vAh;
  gq.Al[0] = qAl; gq.Al[1] = kAl; gq.Al[2] = vAl;
  gq.W[0] = Wq; gq.W[1] = Wk; gq.W[2] = Wv;
  gq.P[0] = Pq; gq.P[1] = Pk; gq.P[2] = Pv;
  mfma_gemm<KSQ><<<3 * 64 * KSQ, 256, 0, stream>>>(gq);

  // 3. cosine-sim + softmax
  dist_kernel<<<NB, 64, 0, stream>>>(Pq, Pk, bq, bk, dist);

  // 4. attention mix -> bf16 hi/lo attn
  attn_kernel<<<NB, 256, 0, stream>>>(Pv, bv, dist, aAh, aAl);

  // 5. output GEMM: 64 coltiles x KSO ksplits = 512 blocks
  GemmArgs go;
  go.Ah[0] = aAh; go.Ah[1] = aAh; go.Ah[2] = aAh;
  go.Al[0] = aAl; go.Al[1] = aAl; go.Al[2] = aAl;
  go.W[0] = Wo; go.W[1] = Wo; go.W[2] = Wo;
  go.P[0] = Po; go.P[1] = Po; go.P[2] = Po;
  mfma_gemm<KSO><<<64 * KSO, 256, 0, stream>>>(go);

  // 6. final reduce + bias
  reduce_kernel<<<256, 256, 0, stream>>>(Po, bo, out);
}